// Round 12
// baseline (1604.547 us; speedup 1.0000x reference)
//
#include <hip/hip_runtime.h>
#include <cstdint>
#include <cstddef>

typedef __bf16 bf16x8 __attribute__((ext_vector_type(8)));
typedef float f32x4 __attribute__((ext_vector_type(4)));
typedef unsigned short ushortx8 __attribute__((ext_vector_type(8)));

// float -> bf16, round-half-up (bitwise-identical to all passing rounds)
__device__ __forceinline__ unsigned short f2bf(float f) {
  union { float f; unsigned int u; } v; v.f = f;
  return (unsigned short)((v.u + 0x8000u) >> 16);
}

// GELU via sigmoid identity (verified in prior rounds)
__device__ __forceinline__ float gelu_s(float x) {
  float x2 = x * x;
  float p = __builtin_fmaf(x2, -0.10294324f, -2.30220819f);
  float e = __builtin_amdgcn_exp2f(x * p);
  return x * __builtin_amdgcn_rcpf(1.0f + e);
}

// async global->LDS, 16B/lane. LDS dest is wave-uniform base + lane*16.
#define GLOAD16(gsrc, ldst)                                                  \
  __builtin_amdgcn_global_load_lds(                                          \
      (const __attribute__((address_space(1))) unsigned int*)(gsrc),         \
      (__attribute__((address_space(3))) unsigned int*)(uintptr_t)(          \
          (char*)(ldst)),                                                    \
      16, 0, 0)

// Swizzled tile: 16B chunk (row R, col8 C in [0,8)) at
// (R>>5)*4096 + ((R&31)*8 + (C ^ (R&7)))*16.
#define SWZ_FRAG(base, R, C8)                                                \
  (*(const bf16x8*)((base) + (((R) >> 5) * 4096) +                           \
                    ((((R)&31) * 8 + ((C8) ^ ((R)&7))) * 16)))

// Signature for converter j: derived from W1 input (garbage-robust, reset-
// free: stale ws from a prior replay implies w1t is also already correct).
__device__ __forceinline__ unsigned sig_val(const float* __restrict__ W1,
                                            int j) {
  int gg = j >> 6, t6 = j & 63;
  union { float f; unsigned u; } w;
  w.f = W1[(gg << 16) + (t6 >> 2) * 4096 + (t6 & 3) * 32];
  return w.u ^ 0x9E3779B9u ^ ((unsigned)j * 2654435761u);
}

// A-tile staging: z (f32) -> reg -> bf16 -> swizzled LDS (proven round 5).
__device__ __forceinline__ void stage_A_f32(const float* __restrict__ ag,
                                            char* lds, int tid, int ko) {
  f32x4 a0[4], a1[4];
#pragma unroll
  for (int it = 0; it < 4; ++it) {
    const float* p = ag + it * 32 * 512 + ko;
    a0[it] = *(const f32x4*)(p);
    a1[it] = *(const f32x4*)(p + 4);
  }
#pragma unroll
  for (int it = 0; it < 4; ++it) {
    ushortx8 r;
    r[0] = f2bf(a0[it][0]); r[1] = f2bf(a0[it][1]);
    r[2] = f2bf(a0[it][2]); r[3] = f2bf(a0[it][3]);
    r[4] = f2bf(a1[it][0]); r[5] = f2bf(a1[it][1]);
    r[6] = f2bf(a1[it][2]); r[7] = f2bf(a1[it][3]);
    *(ushortx8*)(lds + it * 4096 + tid * 16) = r;
  }
}

// ---------------------------------------------------------------------------
// Expert tile (r6-proven on BOTH paths). B from w1t via GLOAD16 when ready;
// else self-staged from W1 f32 (bitwise-identical LDS bytes).
// ---------------------------------------------------------------------------
__device__ __forceinline__ void expert_tile(
    int e, int mbase, bool ready, const float* __restrict__ z,
    const float* __restrict__ W1, const unsigned short* __restrict__ w1t,
    const float* __restrict__ b1, const float* __restrict__ w2,
    const float* __restrict__ b2, float* __restrict__ out, char* lds, int tid,
    int wq, int l15, int l4, int c8s) {
  char* ldsB = lds + 16384;
  const float* ag = z + (size_t)(mbase + (tid >> 3)) * 512 + c8s;
  const unsigned short* bg = w1t + e * 65536 + (tid >> 3) * 512 + c8s;
  const int wr = wq >> 1;  // row half of this wave
  const int wc = wq & 1;   // col half of this wave
  f32x4 acc[4][4] = {};
  for (int kt = 0; kt < 8; ++kt) {
    const int ko = kt * 64;
    if (ready) {
#pragma unroll
      for (int it = 0; it < 4; ++it)
        GLOAD16(bg + it * 32 * 512 + ko, ldsB + it * 4096 + tid * 16);
    } else {
      // self-stage: chunk c -> row R=c>>3 (h), dest col8 c8d=c&7,
      // global d = ko + (c8d^(R&7))*8 + j, source W1[e][d][R].
#pragma unroll
      for (int i = 0; i < 4; ++i) {
        int c = tid + 256 * i;
        int R = c >> 3, c8 = c & 7;
        int dbase = ko + ((c8 ^ (R & 7)) * 8);
        const float* src = W1 + ((size_t)e << 16) + (size_t)dbase * 128 + R;
        ushortx8 v;
#pragma unroll
        for (int j = 0; j < 8; ++j) v[j] = f2bf(src[j * 128]);
        *(ushortx8*)(ldsB + (R >> 5) * 4096 + ((R & 31) * 8 + c8) * 16) = v;
      }
    }
    stage_A_f32(ag, lds, tid, ko);
    __syncthreads();
#pragma unroll
    for (int ks = 0; ks < 2; ++ks) {
      bf16x8 af[4];
#pragma unroll
      for (int rt = 0; rt < 4; ++rt)
        af[rt] = SWZ_FRAG(lds, wr * 64 + rt * 16 + l15, ks * 4 + l4);
#pragma unroll
      for (int ct = 0; ct < 4; ++ct) {
        bf16x8 bfv = SWZ_FRAG(ldsB, wc * 64 + ct * 16 + l15, ks * 4 + l4);
#pragma unroll
        for (int rt = 0; rt < 4; ++rt)
          acc[rt][ct] = __builtin_amdgcn_mfma_f32_16x16x32_bf16(
              af[rt], bfv, acc[rt][ct], 0, 0, 0);
      }
    }
    __syncthreads();
  }
  // epilogue: partial y over this wave's 64 cols, cross-wave combine
  float b1v[4], w2v[4];
#pragma unroll
  for (int ct = 0; ct < 4; ++ct) {
    int n = wc * 64 + ct * 16 + l15;
    b1v[ct] = b1[e * 128 + n];
    w2v[ct] = w2[e * 128 + n];
  }
  float* ylds = (float*)(lds + 32768);  // [4 waves][64 rows]
#pragma unroll
  for (int rt = 0; rt < 4; ++rt) {
#pragma unroll
    for (int i = 0; i < 4; ++i) {
      float s = 0.0f;
#pragma unroll
      for (int ct = 0; ct < 4; ++ct)
        s += gelu_s(acc[rt][ct][i] + b1v[ct]) * w2v[ct];
#pragma unroll
      for (int off = 1; off < 16; off <<= 1) s += __shfl_xor(s, off, 16);
      if (l15 == 0) ylds[wq * 64 + rt * 16 + l4 * 4 + i] = s;
    }
  }
  __syncthreads();
  if (tid < 128) {
    int rl = tid & 63, half = tid >> 6;
    float y = ylds[half * 128 + rl] + ylds[half * 128 + 64 + rl] + b2[e];
    out[(size_t)2097152 + (size_t)(mbase + half * 64 + rl) * 16 + e] = y;
  }
}

// ---------------------------------------------------------------------------
// Logits tile (r6-proven): Wc read directly as f32. No dependencies.
// ---------------------------------------------------------------------------
__device__ __forceinline__ void logits_tile(
    int mbase, const float* __restrict__ z, const float* __restrict__ Wc,
    const float* __restrict__ bc, float* __restrict__ out, char* lds, int tid,
    int wq, int l15, int l4, int c8s) {
  const float* ag = z + (size_t)(mbase + (tid >> 3)) * 512 + c8s;
  f32x4 acc2[2] = {};
  for (int kt = 0; kt < 8; ++kt) {
    const int ko = kt * 64;
    stage_A_f32(ag, lds, tid, ko);
    ushortx8 u0, u1;
#pragma unroll
    for (int j = 0; j < 8; ++j) {
      u0[j] = f2bf(Wc[(ko + l4 * 8 + j) * 16 + l15]);
      u1[j] = f2bf(Wc[(ko + 32 + l4 * 8 + j) * 16 + l15]);
    }
    union { ushortx8 u; bf16x8 b; } p0, p1;
    p0.u = u0; p1.u = u1;
    __syncthreads();
#pragma unroll
    for (int rt = 0; rt < 2; ++rt) {
      bf16x8 a0 = SWZ_FRAG(lds, wq * 32 + rt * 16 + l15, l4);
      acc2[rt] = __builtin_amdgcn_mfma_f32_16x16x32_bf16(a0, p0.b, acc2[rt],
                                                         0, 0, 0);
      bf16x8 a1 = SWZ_FRAG(lds, wq * 32 + rt * 16 + l15, 4 + l4);
      acc2[rt] = __builtin_amdgcn_mfma_f32_16x16x32_bf16(a1, p1.b, acc2[rt],
                                                         0, 0, 0);
    }
    __syncthreads();
  }
  float bcv = bc[l15];
#pragma unroll
  for (int rt = 0; rt < 2; ++rt) {
#pragma unroll
    for (int i = 0; i < 4; ++i) {
      int row = wq * 32 + rt * 16 + l4 * 4 + i;
      float lg = acc2[rt][i] + bcv;
      float mx = lg;
#pragma unroll
      for (int off = 1; off < 16; off <<= 1)
        mx = fmaxf(mx, __shfl_xor(mx, off, 16));
      float ex = __expf(lg - mx);
      float sm = ex;
#pragma unroll
      for (int off = 1; off < 16; off <<= 1) sm += __shfl_xor(sm, off, 16);
      size_t ro = (size_t)(mbase + row) * 16 + l15;
      out[ro] = lg;                 // logits
      out[1048576 + ro] = ex / sm;  // p_g
    }
  }
}

// ---------------------------------------------------------------------------
// Single normal launch, 1024 + 8704 blocks.
//   bid < 1024 : converter — W1 32x32-tile transpose -> w1t bf16 (r6-proven),
//                then threadfence + input-derived signature publish.
//   bid >= 1024: tile, r5's proven mapping on tb = bid-1024 (1024%8==0 so
//                the tb&7 XCD grouping is preserved under round-robin
//                dispatch): xcd=tb&7, t=tb>>3, panel=xcd*64+t/17, r=t%17.
//                r==0 -> logits (no deps); else expert: wave 0 spin-polls
//                the 64 signatures for its expert (bounded, s_sleep backoff)
//                -> fast path; timeout -> r6-proven slow path. Correct under
//                any dispatch order (bounded spin, dependency-free fallback)
//                and any workspace garbage (signatures are input-derived;
//                stale ws => w1t already correct).
// ---------------------------------------------------------------------------
__global__ __launch_bounds__(256, 4) void k_all(
    const float* __restrict__ z, const float* __restrict__ W1,
    const float* __restrict__ Wc, const float* __restrict__ bc,
    const float* __restrict__ b1, const float* __restrict__ w2,
    const float* __restrict__ b2, unsigned short* __restrict__ w1t,
    unsigned int* __restrict__ sig, float* __restrict__ out) {
  __shared__ alignas(16) char lds[33792];
  __shared__ int s_rdy;
  const int tid = threadIdx.x;
  const int bid = blockIdx.x;

  if (bid < 1024) {
    // ---- converter: W1 transpose via 32x32 LDS tile (r6-proven) ----
    float* tile = (float*)lds;  // [32][33]
    int gg = bid >> 6;
    int t6 = bid & 63;  // 16 d-blk x 4 h-blk
    int d0 = (t6 >> 2) * 32;
    int h0 = (t6 & 3) * 32;
    int tx = tid & 31, ty = tid >> 5;
#pragma unroll
    for (int r = 0; r < 4; ++r)
      tile[(r * 8 + ty) * 33 + tx] =
          W1[(gg << 16) + (d0 + r * 8 + ty) * 128 + h0 + tx];
    __syncthreads();
#pragma unroll
    for (int r = 0; r < 4; ++r)
      w1t[(gg << 16) + (h0 + r * 8 + ty) * 512 + d0 + tx] =
          f2bf(tile[tx * 33 + r * 8 + ty]);
    __syncthreads();
    __threadfence();  // release: w1t sub-block visible before signature
    if (tid == 0) atomicExch(&sig[bid], sig_val(W1, bid));
    return;
  }

  const int wq = tid >> 6;
  const int l15 = tid & 15;
  const int l4 = (tid >> 4) & 3;
  const int c8s = (((tid & 7) ^ ((tid >> 3) & 7))) * 8;
  const int tb = bid - 1024;
  const int xcd = tb & 7;
  const int t = tb >> 3;         // 0..1087
  const int pl = t / 17;         // panel-local 0..63
  const int r = t - pl * 17;     // 0..16
  const int mbase = (xcd * 64 + pl) * 128;

  if (r == 0) {
    logits_tile(mbase, z, Wc, bc, out, lds, tid, wq, l15, l4, c8s);
  } else {
    const int e = r - 1;
    // ---- bounded signature spin (wave 0 only; 64 lanes, 1 sig each) ----
    if (tid < 64) {
      const int j = (e << 6) + tid;
      const unsigned expect = sig_val(W1, j);
      int ok = 0;
      for (int it = 0; it < 512; ++it) {
        ok = (atomicAdd(&sig[j], 0u) == expect) ? 1 : 0;
        if (__all(ok)) break;
        __builtin_amdgcn_s_sleep(8);
      }
      if (tid == 0) s_rdy = __all(ok);
    }
    __syncthreads();
    bool ready = (s_rdy != 0);
    if (ready) __threadfence();  // acquire: order w1t reads after signatures
    expert_tile(e, mbase, ready, z, W1, w1t, b1, w2, b2, out, lds, tid, wq,
                l15, l4, c8s);
  }
}

// ---------------------------------------------------------------------------
extern "C" void kernel_launch(void* const* d_in, const int* in_sizes, int n_in,
                              void* d_out, int out_size, void* d_ws,
                              size_t ws_size, hipStream_t stream) {
  const float* z = (const float*)d_in[0];
  const float* Wc = (const float*)d_in[1];
  const float* bc = (const float*)d_in[2];
  const float* W1 = (const float*)d_in[3];
  const float* b1 = (const float*)d_in[4];
  const float* W2 = (const float*)d_in[5];
  const float* b2 = (const float*)d_in[6];
  float* out = (float*)d_out;

  unsigned short* w1t = (unsigned short*)d_ws;            // 2 MB
  unsigned int* sig = (unsigned int*)(w1t + (size_t)16 * 128 * 512);  // 4 KB

  k_all<<<1024 + 8 * 1088, 256, 0, stream>>>(z, W1, Wc, bc, b1, W2, b2, w1t,
                                             sig, out);
}

// Round 13
// 351.697 us; speedup vs baseline: 4.5623x; 4.5623x over previous
//
#include <hip/hip_runtime.h>
#include <cstdint>
#include <cstddef>

typedef __bf16 bf16x8 __attribute__((ext_vector_type(8)));
typedef float f32x4 __attribute__((ext_vector_type(4)));
typedef unsigned int u32x4 __attribute__((ext_vector_type(4)));

// float -> bf16, round-half-up (used for weights; proven all passing rounds)
__device__ __forceinline__ unsigned short f2bf(float f) {
  union { float f; unsigned int u; } v; v.f = f;
  return (unsigned short)((v.u + 0x8000u) >> 16);
}

// Packed f32x2 -> bf16x2 (RNE), single VALU op. gfx950-verified instruction
// (no builtin; inline asm). Replaces ~6 ops of f2bf+pack per 2 elements.
__device__ __forceinline__ unsigned cvtpk(float a, float b) {
  unsigned r;
  asm("v_cvt_pk_bf16_f32 %0, %1, %2" : "=v"(r) : "v"(a), "v"(b));
  return r;  // low16 = bf16(a), high16 = bf16(b)
}

// GELU via sigmoid identity (verified in prior rounds)
__device__ __forceinline__ float gelu_s(float x) {
  float x2 = x * x;
  float p = __builtin_fmaf(x2, -0.10294324f, -2.30220819f);
  float e = __builtin_amdgcn_exp2f(x * p);
  return x * __builtin_amdgcn_rcpf(1.0f + e);
}

// async global->LDS, 16B/lane. LDS dest is wave-uniform base + lane*16.
#define GLOAD16(gsrc, ldst)                                                  \
  __builtin_amdgcn_global_load_lds(                                          \
      (const __attribute__((address_space(1))) unsigned int*)(gsrc),         \
      (__attribute__((address_space(3))) unsigned int*)(uintptr_t)(          \
          (char*)(ldst)),                                                    \
      16, 0, 0)

// Swizzled tile: 16B chunk (row R, col8 C in [0,8)) at
// (R>>5)*4096 + ((R&31)*8 + (C ^ (R&7)))*16.  (proven rounds 0-5)
#define SWZ_FRAG(base, R, C8)                                                \
  (*(const bf16x8*)((base) + (((R) >> 5) * 4096) +                           \
                    ((((R)&31) * 8 + ((C8) ^ ((R)&7))) * 16)))

// A-tile staging: z (f32) -> reg -> bf16 (cvt_pk, RNE) -> swizzled LDS.
// Same addresses/layout as round 5's proven version; only the convert+pack
// is new (16 v_cvt_pk_bf16_f32 per kt vs ~96 VALU ops before).
__device__ __forceinline__ void stage_A_f32(const float* __restrict__ ag,
                                            char* lds, int tid, int ko) {
  f32x4 a0[4], a1[4];
#pragma unroll
  for (int it = 0; it < 4; ++it) {
    const float* p = ag + it * 32 * 512 + ko;
    a0[it] = *(const f32x4*)(p);
    a1[it] = *(const f32x4*)(p + 4);
  }
#pragma unroll
  for (int it = 0; it < 4; ++it) {
    u32x4 v;
    v[0] = cvtpk(a0[it][0], a0[it][1]);
    v[1] = cvtpk(a0[it][2], a0[it][3]);
    v[2] = cvtpk(a1[it][0], a1[it][1]);
    v[3] = cvtpk(a1[it][2], a1[it][3]);
    *(u32x4*)(lds + it * 4096 + tid * 16) = v;
  }
}

// ---------------------------------------------------------------------------
// Expert tile (round-5 proven): A staged from f32 z; B (w1t bf16) GLOAD16.
// ---------------------------------------------------------------------------
__device__ __forceinline__ void expert_tile(
    int e, int mbase, const float* __restrict__ z,
    const unsigned short* __restrict__ w1t, const float* __restrict__ b1,
    const float* __restrict__ w2, const float* __restrict__ b2,
    float* __restrict__ out, char* lds, int tid, int wq, int l15, int l4,
    int c8s) {
  char* ldsB = lds + 16384;
  const float* ag = z + (size_t)(mbase + (tid >> 3)) * 512 + c8s;
  const unsigned short* bg = w1t + e * 65536 + (tid >> 3) * 512 + c8s;
  const int wr = wq >> 1;  // row half of this wave
  const int wc = wq & 1;   // col half of this wave
  f32x4 acc[4][4] = {};
  for (int kt = 0; kt < 8; ++kt) {
    const int ko = kt * 64;
#pragma unroll
    for (int it = 0; it < 4; ++it)
      GLOAD16(bg + it * 32 * 512 + ko, ldsB + it * 4096 + tid * 16);
    stage_A_f32(ag, lds, tid, ko);
    __syncthreads();
#pragma unroll
    for (int ks = 0; ks < 2; ++ks) {
      bf16x8 af[4];
#pragma unroll
      for (int rt = 0; rt < 4; ++rt)
        af[rt] = SWZ_FRAG(lds, wr * 64 + rt * 16 + l15, ks * 4 + l4);
#pragma unroll
      for (int ct = 0; ct < 4; ++ct) {
        bf16x8 bfv = SWZ_FRAG(ldsB, wc * 64 + ct * 16 + l15, ks * 4 + l4);
#pragma unroll
        for (int rt = 0; rt < 4; ++rt)
          acc[rt][ct] = __builtin_amdgcn_mfma_f32_16x16x32_bf16(
              af[rt], bfv, acc[rt][ct], 0, 0, 0);
      }
    }
    __syncthreads();
  }
  // epilogue: partial y over this wave's 64 cols, cross-wave combine
  float b1v[4], w2v[4];
#pragma unroll
  for (int ct = 0; ct < 4; ++ct) {
    int n = wc * 64 + ct * 16 + l15;
    b1v[ct] = b1[e * 128 + n];
    w2v[ct] = w2[e * 128 + n];
  }
  float* ylds = (float*)(lds + 32768);  // [4 waves][64 rows]
#pragma unroll
  for (int rt = 0; rt < 4; ++rt) {
#pragma unroll
    for (int i = 0; i < 4; ++i) {
      float s = 0.0f;
#pragma unroll
      for (int ct = 0; ct < 4; ++ct)
        s += gelu_s(acc[rt][ct][i] + b1v[ct]) * w2v[ct];
#pragma unroll
      for (int off = 1; off < 16; off <<= 1) s += __shfl_xor(s, off, 16);
      if (l15 == 0) ylds[wq * 64 + rt * 16 + l4 * 4 + i] = s;
    }
  }
  __syncthreads();
  if (tid < 128) {
    int rl = tid & 63, half = tid >> 6;
    float y = ylds[half * 128 + rl] + ylds[half * 128 + 64 + rl] + b2[e];
    out[(size_t)2097152 + (size_t)(mbase + half * 64 + rl) * 16 + e] = y;
  }
}

// ---------------------------------------------------------------------------
// Logits tile (round-5 proven): A staged from f32 z; Wc from wct (L2-hot).
// ---------------------------------------------------------------------------
__device__ __forceinline__ void logits_tile(
    int mbase, const float* __restrict__ z,
    const unsigned short* __restrict__ wct, const float* __restrict__ bc,
    float* __restrict__ out, char* lds, int tid, int wq, int l15, int l4,
    int c8s) {
  const float* ag = z + (size_t)(mbase + (tid >> 3)) * 512 + c8s;
  const unsigned short* wb = wct + l15 * 512 + l4 * 8;  // direct, L2-hot
  f32x4 acc2[2] = {};
  for (int kt = 0; kt < 8; ++kt) {
    const int ko = kt * 64;
    stage_A_f32(ag, lds, tid, ko);
    bf16x8 bfr0 = *(const bf16x8*)(wb + ko);
    bf16x8 bfr1 = *(const bf16x8*)(wb + ko + 32);
    __syncthreads();
#pragma unroll
    for (int rt = 0; rt < 2; ++rt) {
      bf16x8 a0 = SWZ_FRAG(lds, wq * 32 + rt * 16 + l15, l4);
      acc2[rt] =
          __builtin_amdgcn_mfma_f32_16x16x32_bf16(a0, bfr0, acc2[rt], 0, 0, 0);
      bf16x8 a1 = SWZ_FRAG(lds, wq * 32 + rt * 16 + l15, 4 + l4);
      acc2[rt] =
          __builtin_amdgcn_mfma_f32_16x16x32_bf16(a1, bfr1, acc2[rt], 0, 0, 0);
    }
    __syncthreads();
  }
  float bcv = bc[l15];
#pragma unroll
  for (int rt = 0; rt < 2; ++rt) {
#pragma unroll
    for (int i = 0; i < 4; ++i) {
      int row = wq * 32 + rt * 16 + l4 * 4 + i;
      float lg = acc2[rt][i] + bcv;
      float mx = lg;
#pragma unroll
      for (int off = 1; off < 16; off <<= 1)
        mx = fmaxf(mx, __shfl_xor(mx, off, 16));
      float ex = __expf(lg - mx);
      float sm = ex;
#pragma unroll
      for (int off = 1; off < 16; off <<= 1) sm += __shfl_xor(sm, off, 16);
      size_t ro = (size_t)(mbase + row) * 16 + l15;
      out[ro] = lg;                 // logits
      out[1048576 + ro] = ex / sm;  // p_g
    }
  }
}

// ---------------------------------------------------------------------------
// Weight conversion (round-5 proven, ~8us):
//   bid < 1024 : W1[g,d,h] -> W1t[g,h,d] bf16 via 32x32 LDS tile
//   bid == 1024: Wc[d,g] -> Wct[g,d] bf16
// ---------------------------------------------------------------------------
__global__ __launch_bounds__(256) void k_convert(
    const float* __restrict__ W1, const float* __restrict__ Wc,
    unsigned short* __restrict__ w1t, unsigned short* __restrict__ wct) {
  int bid = blockIdx.x;
  int tid = threadIdx.x;
  if (bid < 1024) {
    __shared__ float tile[32][33];
    int gg = bid >> 6;
    int t = bid & 63;
    int d0 = (t >> 2) * 32;
    int h0 = (t & 3) * 32;
    int tx = tid & 31, ty = tid >> 5;
#pragma unroll
    for (int r = 0; r < 4; ++r)
      tile[r * 8 + ty][tx] = W1[(gg << 16) + (d0 + r * 8 + ty) * 128 + h0 + tx];
    __syncthreads();
#pragma unroll
    for (int r = 0; r < 4; ++r)
      w1t[(gg << 16) + (h0 + r * 8 + ty) * 512 + d0 + tx] =
          f2bf(tile[tx][r * 8 + ty]);
  } else {
#pragma unroll
    for (int j = 0; j < 32; ++j) {
      int i = j * 256 + tid;
      wct[(i & 15) * 512 + (i >> 4)] = f2bf(Wc[i]);
    }
  }
}

// ---------------------------------------------------------------------------
// Main kernel (round-5 proven mapping, 8704 blocks):
//   xcd = bid&7, t = bid>>3, panel = xcd*64 + t/17, r = t%17.
//   r==0 -> logits; else expert e = r-1. Dispatcher-enforced per-XCD window
//   keeps each z panel L2-hot across its 17 consecutive tiles (FETCH 75MB).
// ---------------------------------------------------------------------------
__global__ __launch_bounds__(256, 4) void k_main(
    const float* __restrict__ z, const unsigned short* __restrict__ w1t,
    const unsigned short* __restrict__ wct, const float* __restrict__ bc,
    const float* __restrict__ b1, const float* __restrict__ w2,
    const float* __restrict__ b2, float* __restrict__ out) {
  __shared__ alignas(16) char lds[33792];
  const int tid = threadIdx.x;
  const int wq = tid >> 6;
  const int l15 = tid & 15;
  const int l4 = (tid >> 4) & 3;
  const int c8s = (((tid & 7) ^ ((tid >> 3) & 7))) * 8;
  const int xcd = blockIdx.x & 7;
  const int t = blockIdx.x >> 3;    // 0..1087
  const int pl = t / 17;            // panel-local 0..63
  const int r = t - pl * 17;        // 0..16
  const int mbase = (xcd * 64 + pl) * 128;
  if (r == 0)
    logits_tile(mbase, z, wct, bc, out, lds, tid, wq, l15, l4, c8s);
  else
    expert_tile(r - 1, mbase, z, w1t, b1, w2, b2, out, lds, tid, wq, l15, l4,
                c8s);
}

// ---------------------------------------------------------------------------
extern "C" void kernel_launch(void* const* d_in, const int* in_sizes, int n_in,
                              void* d_out, int out_size, void* d_ws,
                              size_t ws_size, hipStream_t stream) {
  const float* z = (const float*)d_in[0];
  const float* Wc = (const float*)d_in[1];
  const float* bc = (const float*)d_in[2];
  const float* W1 = (const float*)d_in[3];
  const float* b1 = (const float*)d_in[4];
  const float* W2 = (const float*)d_in[5];
  const float* b2 = (const float*)d_in[6];
  float* out = (float*)d_out;

  unsigned short* w1t = (unsigned short*)d_ws;           // 2 MB
  unsigned short* wct = w1t + (size_t)16 * 128 * 512;    // 16 KB

  k_convert<<<1024 + 1, 256, 0, stream>>>(W1, Wc, w1t, wct);
  k_main<<<8 * 1088, 256, 0, stream>>>(z, w1t, wct, bc, b1, W2, b2, out);
}